// Round 12
// baseline (169.619 us; speedup 1.0000x reference)
//
#include <hip/hip_runtime.h>
#include <stdint.h>

// Problem constants
#define BB 2
#define SS 2048
#define HH 1024
#define NH 16
#define HD 64

#define LOG2E 1.4426950408889634f
#define QSCALE (0.125f * LOG2E)   // folded into Q at GEMM epilogue

typedef short bfrag  __attribute__((ext_vector_type(8)));   // 8 x bf16 (4 VGPRs)
typedef short bfrag4 __attribute__((ext_vector_type(4)));   // 4 x bf16 (2 VGPRs)
typedef float f32x4  __attribute__((ext_vector_type(4)));

__device__ __forceinline__ short f2bf(float f) {
    union { float f; uint32_t u; } v; v.f = f;
    uint32_t r = (v.u + 0x7fffu + ((v.u >> 16) & 1u)) >> 16;
    return (short)r;
}

// pack two f32 -> one dword of bf16 (lo = a, hi = b)
__device__ __forceinline__ uint32_t pack_bf16(float a, float b) {
#if __has_builtin(__builtin_amdgcn_cvt_pk_bf16_f32)
    auto t = __builtin_amdgcn_cvt_pk_bf16_f32(a, b);   // RNE, single VALU op
    uint32_t u; __builtin_memcpy(&u, &t, 4);
    return u;
#else
    uint32_t ua = __float_as_uint(a) + 0x8000u;
    uint32_t ub = __float_as_uint(b) + 0x8000u;
    return __builtin_amdgcn_perm(ub, ua, 0x07060302u);
#endif
}

// fused fp32->bf16 conversion: hidden (1048576 f4) + Wq/Wk/Wv (262144 f4 each,
// into contiguous Wcat) + mask*LOG2E (1024 f4, fp32 out). grid 7172.
__global__ __launch_bounds__(256) void cvt_all(
    const float* __restrict__ X,  const float* __restrict__ Wq,
    const float* __restrict__ Wk, const float* __restrict__ Wv,
    const float* __restrict__ mask,
    short* __restrict__ Xb, short* __restrict__ Wcat,
    float* __restrict__ maskl)
{
    int i = blockIdx.x * 256 + threadIdx.x;
    if (i >= 1835008) {
        int off = i - 1835008;   // 0..1023
        float4 f = ((const float4*)mask)[off];
        f.x *= LOG2E; f.y *= LOG2E; f.z *= LOG2E; f.w *= LOG2E;
        ((float4*)maskl)[off] = f;
        return;
    }
    const float* src; short* dst; int off;
    if (i < 1048576)      { src = X;  dst = Xb;                 off = i; }
    else if (i < 1310720) { src = Wq; dst = Wcat;               off = i - 1048576; }
    else if (i < 1572864) { src = Wk; dst = Wcat + 1048576;     off = i - 1310720; }
    else                  { src = Wv; dst = Wcat + 2097152;     off = i - 1572864; }
    float4 f = ((const float4*)src)[off];
    short4 s;
    s.x = f2bf(f.x); s.y = f2bf(f.y); s.z = f2bf(f.z); s.w = f2bf(f.w);
    ((short4*)dst)[off] = s;
}

__device__ __forceinline__ void gload_lds16(const void* g, void* lds) {
    __builtin_amdgcn_global_load_lds(
        (__attribute__((address_space(1))) void*)(uintptr_t)g,
        (__attribute__((address_space(3))) void*)(uintptr_t)lds,
        16, 0, 0);
}

// Fused QKV GEMM (BK=64, 2-barrier K-loop — the known-good config).
// C[m][n] = sum_k X[m][k] * Wcat[n][k] + bias, M=4096 N=3072 K=1024.
// n in [0,1024) -> Q (pre-scaled by QSCALE), [1024,2048) -> K,
// [2048,3072) -> V^T [bh][d][s] with k-PERMUTED s within each 64-block:
// pos(k) = (g*4+q)*8 + h*4 + j for k = 32g+16h+4q+j (see attn PV reads).
// (256,4): 4 blocks/CU (16 waves) — occupancy experiment vs (256,3)'s 12 waves;
// est. ~115-120 VGPR <= 128 cap. Spill tripwire: WRITE_SIZE balloons.
__global__ __launch_bounds__(256, 4) void qkv_gemm(
    const short* __restrict__ X, const short* __restrict__ Wcat,
    const float* __restrict__ bq, const float* __restrict__ bk, const float* __restrict__ bv,
    short* __restrict__ Qo, short* __restrict__ Ko, short* __restrict__ Vo)
{
    // main loop: As = smem[0..8191], Bs = smem[8192..16383] (shorts)
    // epilogue: reused as T[128][136] (17408 shorts)
    __shared__ __align__(16) short smem[17408];

    const int tid  = threadIdx.x;
    const int wave = tid >> 6, lane = tid & 63;
    const int quad = lane >> 4, l15 = lane & 15;
    const int mTile = blockIdx.y * 128;
    const int nTile = blockIdx.x * 128;
    const int z = nTile >> 10;                 // 0=Q,1=K,2=V (block-uniform)
    const int nLocT = nTile & 1023;
    const float* bias = (z == 0) ? bq : (z == 1) ? bk : bv;

    f32x4 acc[4][4];
#pragma unroll
    for (int i = 0; i < 4; ++i)
#pragma unroll
        for (int j = 0; j < 4; ++j) acc[i][j] = (f32x4)0.0f;

    const int srow  = lane >> 3;   // 0..7
    const int c_lin = lane & 7;
    const int mBase = (wave >> 1) * 64;
    const int nBase = (wave & 1) * 64;

    for (int k0 = 0; k0 < 1024; k0 += 64) {
        __syncthreads();
#pragma unroll
        for (int i = 0; i < 4; ++i) {
            int row = i * 32 + wave * 8 + srow;
            int cg  = c_lin ^ (row & 7);
            gload_lds16(X + (size_t)(mTile + row) * 1024 + k0 + cg * 8,
                        (char*)smem + i * 4096 + wave * 1024);
            gload_lds16(Wcat + (size_t)(nTile + row) * 1024 + k0 + cg * 8,
                        (char*)smem + 16384 + i * 4096 + wave * 1024);
        }
        __syncthreads();

#pragma unroll
        for (int kt = 0; kt < 2; ++kt) {
            bfrag af[4], bf[4];
#pragma unroll
            for (int t = 0; t < 4; ++t) {
                int arow = mBase + t * 16 + l15;
                int aslot = (kt * 4 + quad) ^ (arow & 7);
                af[t] = *(const bfrag*)((const char*)smem + arow * 128 + aslot * 16);
                int brow = nBase + t * 16 + l15;
                int bslot = (kt * 4 + quad) ^ (brow & 7);
                bf[t] = *(const bfrag*)((const char*)smem + 16384 + brow * 128 + bslot * 16);
            }
#pragma unroll
            for (int mt = 0; mt < 4; ++mt)
#pragma unroll
                for (int ct = 0; ct < 4; ++ct)
                    acc[mt][ct] = __builtin_amdgcn_mfma_f32_16x16x32_bf16(
                        af[mt], bf[ct], acc[mt][ct], 0, 0, 0);
        }
    }

    __syncthreads();   // main-loop LDS reads complete before T overwrite
    const int b = mTile >> 11, sBase = mTile & 2047;

    if (z == 2) {
        // T[n-local][s-local], pitch 136 -> k-permuted coalesced V^T stores
#pragma unroll
        for (int mt = 0; mt < 4; ++mt)
#pragma unroll
            for (int ct = 0; ct < 4; ++ct)
#pragma unroll
                for (int r = 0; r < 4; ++r) {
                    int nl = nBase + ct * 16 + l15;
                    int sl = mBase + mt * 16 + quad * 4 + r;
                    smem[nl * 136 + sl] = f2bf(acc[mt][ct][r] + bias[nLocT + nl]);
                }
        __syncthreads();
#pragma unroll
        for (int p = 0; p < 8; ++p) {
            int nl = p * 16 + (tid >> 4);     // d-row 0..127
            int cg = tid & 15;                // 16B chunk within 128-s tile
            int blk = cg >> 3;                // which 64-s block
            int c2  = cg & 7;                 // chunk within block: g = c2>>2, q = c2&3
            int base = blk * 64 + (c2 >> 2) * 32 + (c2 & 3) * 4;   // h=0 source
            int2 lo = *(const int2*)(smem + nl * 136 + base);       // k = ..+0..3
            int2 hi = *(const int2*)(smem + nl * 136 + base + 16);  // k = ..+16..19
            int4 v; v.x = lo.x; v.y = lo.y; v.z = hi.x; v.w = hi.y;
            int ng = nLocT + nl, hh = ng >> 6, d = ng & 63;
            *(int4*)(Vo + ((size_t)(b * 16 + hh) * 64 + d) * 2048 + sBase + cg * 8) = v;
        }
    } else {
        short* Out = (z == 0) ? Qo : Ko;
        float scale = (z == 0) ? QSCALE : 1.0f;
        // T[s-local][n-local], pitch 136 -> coalesced [bh][s][d] stores
#pragma unroll
        for (int mt = 0; mt < 4; ++mt)
#pragma unroll
            for (int ct = 0; ct < 4; ++ct)
#pragma unroll
                for (int r = 0; r < 4; ++r) {
                    int ml = mBase + mt * 16 + quad * 4 + r;
                    int nl = nBase + ct * 16 + l15;
                    smem[ml * 136 + nl] = f2bf((acc[mt][ct][r] + bias[nLocT + nl]) * scale);
                }
        __syncthreads();
#pragma unroll
        for (int p = 0; p < 8; ++p) {
            int ml = p * 16 + (tid >> 4);
            int c  = tid & 15;
            bfrag v8 = *(const bfrag*)(smem + ml * 136 + c * 8);
            int s  = sBase + ml;
            int nl = nLocT + c * 8, hh = nl >> 6, d = nl & 63;
            *(bfrag*)(Out + (((size_t)(b * 16 + hh) << 11) + s) * 64 + d) = v8;
        }
    }
}

// Flash attention (no-max softmax, log2 domain; Q pre-scaled by 0.125*log2e).
// One block = 64 Q rows of one (b,h); 4 waves x 16 rows. Grid 1024 (flattened).
// XCD-affinity swizzle: linear dispatch id -> (bh, qtile) such that all 32
// q-blocks of one bh share id mod 32 -> same XCD under round-robin dispatch;
// 4 bh/XCD x 512 KB K+V = 2 MB < 4 MB L2 -> K/V L2-resident per XCD.
// Bc=64; LDS double-buffer with DMA staging, ONE barrier/iter.
// Mask folded into QK MFMA C-operand; P packed via v_cvt_pk_bf16_f32.
// V is k-permuted in global -> b128 conflict-free V reads feeding MFMA pairs.
__global__ __launch_bounds__(256, 4) void attn_kernel(
    const short* __restrict__ Qb, const short* __restrict__ Kb, const short* __restrict__ Vb,
    const float* __restrict__ maskl, float* __restrict__ out)
{
    __shared__ __align__(16) char smem[32768];
    // stage = 16384 B: K tile [64][64] bf16 @+0 (128B rows, XOR-swizzled 16B chunks),
    //                  V^T tile [64 d][64 k-permuted] bf16 @+8192 (same layout)

    const int tid  = threadIdx.x;
    const int wave = tid >> 6, lane = tid & 63;
    const int quad = lane >> 4, l15 = lane & 15;

    // XCD-affinity remap of the 1024-block launch
    const int id = blockIdx.x;
    const int bh = ((id & 7) << 2) | ((id >> 3) & 3);   // 0..31
    const int qt = id >> 5;                             // 0..31
    const int b  = bh >> 4, h = bh & 15;
    const int qBase = qt * 64 + wave * 16;

    // staging source byte offsets (wave handles chunks wave*128 + i*64 + lane)
    int ksrc[2], vsrc[2];
#pragma unroll
    for (int i = 0; i < 2; ++i) {
        int ci = wave * 128 + i * 64 + lane;
        int r = ci >> 3, c = ci & 7;
        int cs = (c ^ (r & 7)) * 16;
        ksrc[i] = r * 128  + cs;    // K source: row stride 64 shorts = 128B
        vsrc[i] = r * 4096 + cs;    // V^T source: row stride 2048 shorts = 4096B
    }
    const char* kBase = (const char*)(Kb + (size_t)bh * SS * HD);
    const char* vBase = (const char*)(Vb + (size_t)bh * HD * SS);
    const char* mSrc  = (const char*)(maskl + b * SS) + quad * 16;

    // Q fragment (MFMA B-operand): Q[qrow=l15][k=quad*8+j], pre-scaled
    const short* Qp = Qb + ((size_t)bh * SS + qBase) * HD;
    bfrag qf[2];
#pragma unroll
    for (int kt = 0; kt < 2; ++kt)
        qf[kt] = *(const bfrag*)(Qp + (size_t)l15 * HD + kt * 32 + quad * 8);

    // j-invariant LDS read offsets (within a stage)
    int kAddr[2];
#pragma unroll
    for (int kt = 0; kt < 2; ++kt)
        kAddr[kt] = l15 * 128 + (((kt * 4 + quad) ^ (l15 & 7)) * 16);
    int vAddr[2];
#pragma unroll
    for (int g = 0; g < 2; ++g)
        vAddr[g] = 8192 + l15 * 128 + (((g * 4 + quad) ^ (l15 & 7)) * 16);

    const f32x4 z4 = (f32x4)0.0f;
    const bfrag4 ones = {0x3F80, 0x3F80, 0x3F80, 0x3F80};  // bf16 1.0 x4

    f32x4 oacc[4], ol = z4;
#pragma unroll
    for (int dt = 0; dt < 4; ++dt) oacc[dt] = z4;

    // prologue: stage tile 0 into buffer 0
#pragma unroll
    for (int i = 0; i < 2; ++i) {
        gload_lds16(kBase + ksrc[i], smem + wave * 2048 + i * 1024);
        gload_lds16(vBase + vsrc[i], smem + 8192 + wave * 2048 + i * 1024);
    }

    auto astep = [&](int CUR, int NXT, int jn, int pref) {
        __syncthreads();   // tile-j loads landed; prior compute done (buffer free)
        if (pref) {
#pragma unroll
            for (int i = 0; i < 2; ++i) {
                gload_lds16(kBase + jn * 8192 + ksrc[i], smem + NXT + wave * 2048 + i * 1024);
                gload_lds16(vBase + jn * 128  + vsrc[i], smem + NXT + 8192 + wave * 2048 + i * 1024);
            }
        }

        // mask (pre-multiplied by log2e) == C-layout broadcast -> QK acc init
        f32x4 mvl[4];
#pragma unroll
        for (int ct = 0; ct < 4; ++ct)
            mvl[ct] = *(const f32x4*)(mSrc + ct * 64);
        mSrc += 256;

        // S^T = K * Q^T + mask : s[ct] holds C[kcol=ct*16+quad*4+r][qrow=l15]
        f32x4 s[4];
#pragma unroll
        for (int ct = 0; ct < 4; ++ct) {
            bfrag kf0 = *(const bfrag*)(smem + CUR + kAddr[0] + ct * 2048);
            bfrag kf1 = *(const bfrag*)(smem + CUR + kAddr[1] + ct * 2048);
            s[ct] = __builtin_amdgcn_mfma_f32_16x16x32_bf16(kf0, qf[0], mvl[ct], 0, 0, 0);
            s[ct] = __builtin_amdgcn_mfma_f32_16x16x32_bf16(kf1, qf[1], s[ct],   0, 0, 0);
        }

        // softmax numerators: 16 exp + 8 pack per iter
        bfrag4 pf[4];
#pragma unroll
        for (int ct = 0; ct < 4; ++ct) {
            float e0 = __builtin_amdgcn_exp2f(s[ct][0]);
            float e1 = __builtin_amdgcn_exp2f(s[ct][1]);
            float e2 = __builtin_amdgcn_exp2f(s[ct][2]);
            float e3 = __builtin_amdgcn_exp2f(s[ct][3]);
            union { uint32_t u[2]; bfrag4 v; } cvt;
            cvt.u[0] = pack_bf16(e0, e1);
            cvt.u[1] = pack_bf16(e2, e3);
            pf[ct] = cvt.v;
        }

        // O += P*V : one b128 V read feeds the (2g, 2g+1) MFMA pair ; l += P*ones
#pragma unroll
        for (int dt = 0; dt < 4; ++dt) {
#pragma unroll
            for (int g = 0; g < 2; ++g) {
                bfrag v = *(const bfrag*)(smem + CUR + vAddr[g] + dt * 2048);
                bfrag4 vlo = __builtin_shufflevector(v, v, 0, 1, 2, 3);
                bfrag4 vhi = __builtin_shufflevector(v, v, 4, 5, 6, 7);
                oacc[dt] = __builtin_amdgcn_mfma_f32_16x16x16bf16_1k(pf[2 * g],     vlo, oacc[dt], 0, 0, 0);
                oacc[dt] = __builtin_amdgcn_mfma_f32_16x16x16bf16_1k(pf[2 * g + 1], vhi, oacc[dt], 0, 0, 0);
            }
        }
#pragma unroll
        for (int ct = 0; ct < 4; ++ct)
            ol = __builtin_amdgcn_mfma_f32_16x16x16bf16_1k(pf[ct], ones, ol, 0, 0, 0);
    };

    for (int jj = 0; jj < 16; ++jj) {
        astep(0,     16384, 2 * jj + 1, 1);
        astep(16384, 0,     2 * jj + 2, jj < 15);
    }

    // epilogue: out[b][qrow][h*64+d] fp32; O rows = quad*4+r, cols = l15 (+16*dt)
#pragma unroll
    for (int r = 0; r < 4; ++r) {
        float linv = 1.0f / ol[r];
        int qrow = qBase + quad * 4 + r;
#pragma unroll
        for (int dt = 0; dt < 4; ++dt)
            out[((size_t)(b * SS + qrow)) * HH + h * 64 + dt * 16 + l15] =
                oacc[dt][r] * linv;
    }
}

extern "C" void kernel_launch(void* const* d_in, const int* in_sizes, int n_in,
                              void* d_out, int out_size, void* d_ws, size_t ws_size,
                              hipStream_t stream) {
    const float* hs   = (const float*)d_in[0];
    const float* mask = (const float*)d_in[1];
    const float* Wq   = (const float*)d_in[2];
    const float* bq   = (const float*)d_in[3];
    const float* Wk   = (const float*)d_in[4];
    const float* bk   = (const float*)d_in[5];
    const float* Wv   = (const float*)d_in[6];
    const float* bv   = (const float*)d_in[7];
    float* out = (float*)d_out;

    char* ws = (char*)d_ws;
    short* Xb    = (short*)(ws);                      // [4096][1024] bf16, 8 MiB
    short* Wcat  = (short*)(ws + (8ull  << 20));      // [3072][1024] bf16, 6 MiB (Wq|Wk|Wv)
    short* Qb    = (short*)(ws + (14ull << 20));      // [bh][s][d] 8 MiB (pre-scaled)
    short* Kb    = (short*)(ws + (22ull << 20));      // [bh][s][d] 8 MiB
    short* Vb    = (short*)(ws + (30ull << 20));      // [bh][d][s-permuted] 8 MiB
    float* maskl = (float*)(ws + (38ull << 20));      // [B][S] fp32, 16 KiB

    cvt_all<<<7172, 256, 0, stream>>>(hs, Wq, Wk, Wv, mask, Xb, Wcat, maskl);

    qkv_gemm<<<dim3(24, 32), 256, 0, stream>>>(Xb, Wcat, bq, bk, bv, Qb, Kb, Vb);

    attn_kernel<<<1024, 256, 0, stream>>>(Qb, Kb, Vb, maskl, out);
}

// Round 13
// 165.618 us; speedup vs baseline: 1.0242x; 1.0242x over previous
//
#include <hip/hip_runtime.h>
#include <stdint.h>

// Problem constants
#define BB 2
#define SS 2048
#define HH 1024
#define NH 16
#define HD 64

#define LOG2E 1.4426950408889634f
#define QSCALE (0.125f * LOG2E)   // folded into Q at GEMM epilogue

typedef short bfrag  __attribute__((ext_vector_type(8)));   // 8 x bf16 (4 VGPRs)
typedef short bfrag4 __attribute__((ext_vector_type(4)));   // 4 x bf16 (2 VGPRs)
typedef float f32x4  __attribute__((ext_vector_type(4)));

__device__ __forceinline__ short f2bf(float f) {
    union { float f; uint32_t u; } v; v.f = f;
    uint32_t r = (v.u + 0x7fffu + ((v.u >> 16) & 1u)) >> 16;
    return (short)r;
}

// pack two f32 -> one dword of bf16 (lo = a, hi = b)
__device__ __forceinline__ uint32_t pack_bf16(float a, float b) {
#if __has_builtin(__builtin_amdgcn_cvt_pk_bf16_f32)
    auto t = __builtin_amdgcn_cvt_pk_bf16_f32(a, b);   // RNE, single VALU op
    uint32_t u; __builtin_memcpy(&u, &t, 4);
    return u;
#else
    uint32_t ua = __float_as_uint(a) + 0x8000u;
    uint32_t ub = __float_as_uint(b) + 0x8000u;
    return __builtin_amdgcn_perm(ub, ua, 0x07060302u);
#endif
}

// fused fp32->bf16 conversion: hidden (1048576 f4) + Wq/Wk/Wv (262144 f4 each,
// into contiguous Wcat) + mask*LOG2E (1024 f4, fp32 out). grid 7172.
__global__ __launch_bounds__(256) void cvt_all(
    const float* __restrict__ X,  const float* __restrict__ Wq,
    const float* __restrict__ Wk, const float* __restrict__ Wv,
    const float* __restrict__ mask,
    short* __restrict__ Xb, short* __restrict__ Wcat,
    float* __restrict__ maskl)
{
    int i = blockIdx.x * 256 + threadIdx.x;
    if (i >= 1835008) {
        int off = i - 1835008;   // 0..1023
        float4 f = ((const float4*)mask)[off];
        f.x *= LOG2E; f.y *= LOG2E; f.z *= LOG2E; f.w *= LOG2E;
        ((float4*)maskl)[off] = f;
        return;
    }
    const float* src; short* dst; int off;
    if (i < 1048576)      { src = X;  dst = Xb;                 off = i; }
    else if (i < 1310720) { src = Wq; dst = Wcat;               off = i - 1048576; }
    else if (i < 1572864) { src = Wk; dst = Wcat + 1048576;     off = i - 1310720; }
    else                  { src = Wv; dst = Wcat + 2097152;     off = i - 1572864; }
    float4 f = ((const float4*)src)[off];
    short4 s;
    s.x = f2bf(f.x); s.y = f2bf(f.y); s.z = f2bf(f.z); s.w = f2bf(f.w);
    ((short4*)dst)[off] = s;
}

__device__ __forceinline__ void gload_lds16(const void* g, void* lds) {
    __builtin_amdgcn_global_load_lds(
        (__attribute__((address_space(1))) void*)(uintptr_t)g,
        (__attribute__((address_space(3))) void*)(uintptr_t)lds,
        16, 0, 0);
}

// Fused QKV GEMM (BK=64, 2-barrier K-loop, (256,3) — the known-good config;
// (256,4) regressed ~3.5 us in R12).
// C[m][n] = sum_k X[m][k] * Wcat[n][k] + bias, M=4096 N=3072 K=1024.
// n in [0,1024) -> Q (pre-scaled by QSCALE), [1024,2048) -> K,
// [2048,3072) -> V^T [bh][d][s] with k-PERMUTED s within each 64-block:
// pos(k) = (g*4+q)*8 + h*4 + j for k = 32g+16h+4q+j (see attn PV reads).
__global__ __launch_bounds__(256, 3) void qkv_gemm(
    const short* __restrict__ X, const short* __restrict__ Wcat,
    const float* __restrict__ bq, const float* __restrict__ bk, const float* __restrict__ bv,
    short* __restrict__ Qo, short* __restrict__ Ko, short* __restrict__ Vo)
{
    // main loop: As = smem[0..8191], Bs = smem[8192..16383] (shorts)
    // epilogue: reused as T[128][136] (17408 shorts)
    __shared__ __align__(16) short smem[17408];

    const int tid  = threadIdx.x;
    const int wave = tid >> 6, lane = tid & 63;
    const int quad = lane >> 4, l15 = lane & 15;
    const int mTile = blockIdx.y * 128;
    const int nTile = blockIdx.x * 128;
    const int z = nTile >> 10;                 // 0=Q,1=K,2=V (block-uniform)
    const int nLocT = nTile & 1023;
    const float* bias = (z == 0) ? bq : (z == 1) ? bk : bv;

    f32x4 acc[4][4];
#pragma unroll
    for (int i = 0; i < 4; ++i)
#pragma unroll
        for (int j = 0; j < 4; ++j) acc[i][j] = (f32x4)0.0f;

    const int srow  = lane >> 3;   // 0..7
    const int c_lin = lane & 7;
    const int mBase = (wave >> 1) * 64;
    const int nBase = (wave & 1) * 64;

    for (int k0 = 0; k0 < 1024; k0 += 64) {
        __syncthreads();
#pragma unroll
        for (int i = 0; i < 4; ++i) {
            int row = i * 32 + wave * 8 + srow;
            int cg  = c_lin ^ (row & 7);
            gload_lds16(X + (size_t)(mTile + row) * 1024 + k0 + cg * 8,
                        (char*)smem + i * 4096 + wave * 1024);
            gload_lds16(Wcat + (size_t)(nTile + row) * 1024 + k0 + cg * 8,
                        (char*)smem + 16384 + i * 4096 + wave * 1024);
        }
        __syncthreads();

#pragma unroll
        for (int kt = 0; kt < 2; ++kt) {
            bfrag af[4], bf[4];
#pragma unroll
            for (int t = 0; t < 4; ++t) {
                int arow = mBase + t * 16 + l15;
                int aslot = (kt * 4 + quad) ^ (arow & 7);
                af[t] = *(const bfrag*)((const char*)smem + arow * 128 + aslot * 16);
                int brow = nBase + t * 16 + l15;
                int bslot = (kt * 4 + quad) ^ (brow & 7);
                bf[t] = *(const bfrag*)((const char*)smem + 16384 + brow * 128 + bslot * 16);
            }
#pragma unroll
            for (int mt = 0; mt < 4; ++mt)
#pragma unroll
                for (int ct = 0; ct < 4; ++ct)
                    acc[mt][ct] = __builtin_amdgcn_mfma_f32_16x16x32_bf16(
                        af[mt], bf[ct], acc[mt][ct], 0, 0, 0);
        }
    }

    __syncthreads();   // main-loop LDS reads complete before T overwrite
    const int b = mTile >> 11, sBase = mTile & 2047;

    if (z == 2) {
        // T[n-local][s-local], pitch 136 -> k-permuted coalesced V^T stores
#pragma unroll
        for (int mt = 0; mt < 4; ++mt)
#pragma unroll
            for (int ct = 0; ct < 4; ++ct)
#pragma unroll
                for (int r = 0; r < 4; ++r) {
                    int nl = nBase + ct * 16 + l15;
                    int sl = mBase + mt * 16 + quad * 4 + r;
                    smem[nl * 136 + sl] = f2bf(acc[mt][ct][r] + bias[nLocT + nl]);
                }
        __syncthreads();
#pragma unroll
        for (int p = 0; p < 8; ++p) {
            int nl = p * 16 + (tid >> 4);     // d-row 0..127
            int cg = tid & 15;                // 16B chunk within 128-s tile
            int blk = cg >> 3;                // which 64-s block
            int c2  = cg & 7;                 // chunk within block: g = c2>>2, q = c2&3
            int base = blk * 64 + (c2 >> 2) * 32 + (c2 & 3) * 4;   // h=0 source
            int2 lo = *(const int2*)(smem + nl * 136 + base);       // k = ..+0..3
            int2 hi = *(const int2*)(smem + nl * 136 + base + 16);  // k = ..+16..19
            int4 v; v.x = lo.x; v.y = lo.y; v.z = hi.x; v.w = hi.y;
            int ng = nLocT + nl, hh = ng >> 6, d = ng & 63;
            *(int4*)(Vo + ((size_t)(b * 16 + hh) * 64 + d) * 2048 + sBase + cg * 8) = v;
        }
    } else {
        short* Out = (z == 0) ? Qo : Ko;
        float scale = (z == 0) ? QSCALE : 1.0f;
        // T[s-local][n-local], pitch 136 -> coalesced [bh][s][d] stores
#pragma unroll
        for (int mt = 0; mt < 4; ++mt)
#pragma unroll
            for (int ct = 0; ct < 4; ++ct)
#pragma unroll
                for (int r = 0; r < 4; ++r) {
                    int ml = mBase + mt * 16 + quad * 4 + r;
                    int nl = nBase + ct * 16 + l15;
                    smem[ml * 136 + nl] = f2bf((acc[mt][ct][r] + bias[nLocT + nl]) * scale);
                }
        __syncthreads();
#pragma unroll
        for (int p = 0; p < 8; ++p) {
            int ml = p * 16 + (tid >> 4);
            int c  = tid & 15;
            bfrag v8 = *(const bfrag*)(smem + ml * 136 + c * 8);
            int s  = sBase + ml;
            int nl = nLocT + c * 8, hh = nl >> 6, d = nl & 63;
            *(bfrag*)(Out + (((size_t)(b * 16 + hh) << 11) + s) * 64 + d) = v8;
        }
    }
}

// Flash attention (no-max softmax, log2 domain; Q pre-scaled by 0.125*log2e).
// 32 Q-rows per wave (two 16-row halves sharing every K/V LDS read and mask
// load) -> LDS read bytes per Q-row HALVED vs 16-row waves. LDS pipe was the
// binding resource at R12 (~73% of wall by cycle ledger).
// 4-wave blocks of 128 Q rows; grid 512 (2 blocks/CU, 8 waves/CU).
// XCD-affinity: bh = (id&7)*4 + ((id>>3)&3) -> 4 bh per XCD, K+V 2MB < L2.
// Bc=64; LDS double-buffer with DMA staging, ONE barrier/iter.
// Mask folded into QK MFMA C-operand; P packed via v_cvt_pk_bf16_f32.
// V k-permuted in global -> b128 conflict-free V reads feeding MFMA pairs.
__global__ __launch_bounds__(256, 2) void attn_kernel(
    const short* __restrict__ Qb, const short* __restrict__ Kb, const short* __restrict__ Vb,
    const float* __restrict__ maskl, float* __restrict__ out)
{
    __shared__ __align__(16) char smem[32768];
    // stage = 16384 B: K tile [64][64] bf16 @+0 (128B rows, XOR-swizzled 16B chunks),
    //                  V^T tile [64 d][64 k-permuted] bf16 @+8192 (same layout)

    const int tid  = threadIdx.x;
    const int wave = tid >> 6, lane = tid & 63;
    const int quad = lane >> 4, l15 = lane & 15;

    // XCD-affinity remap of the 512-block launch
    const int id = blockIdx.x;
    const int slot = id >> 3;                            // 0..63
    const int bh = ((id & 7) << 2) | (slot & 3);         // 0..31, fixed per XCD
    const int qt = slot >> 2;                            // 0..15
    const int b  = bh >> 4, h = bh & 15;
    const int qBase = qt * 128 + wave * 32;

    // staging source byte offsets (wave handles chunks wave*128 + i*64 + lane)
    int ksrc[2], vsrc[2];
#pragma unroll
    for (int i = 0; i < 2; ++i) {
        int ci = wave * 128 + i * 64 + lane;
        int r = ci >> 3, c = ci & 7;
        int cs = (c ^ (r & 7)) * 16;
        ksrc[i] = r * 128  + cs;    // K source: row stride 64 shorts = 128B
        vsrc[i] = r * 4096 + cs;    // V^T source: row stride 2048 shorts = 4096B
    }
    const char* kBase = (const char*)(Kb + (size_t)bh * SS * HD);
    const char* vBase = (const char*)(Vb + (size_t)bh * HD * SS);
    const char* mSrc  = (const char*)(maskl + b * SS) + quad * 16;

    // Q fragments (MFMA B-operand): Q[qrow=hf*16+l15][k=quad*8+j], pre-scaled
    const short* Qp = Qb + ((size_t)bh * SS + qBase) * HD;
    bfrag qf[2][2];
#pragma unroll
    for (int hf = 0; hf < 2; ++hf)
#pragma unroll
        for (int kt = 0; kt < 2; ++kt)
            qf[hf][kt] = *(const bfrag*)(Qp + (size_t)(hf * 16 + l15) * HD + kt * 32 + quad * 8);

    // j-invariant LDS read offsets (within a stage)
    int kAddr[2];
#pragma unroll
    for (int kt = 0; kt < 2; ++kt)
        kAddr[kt] = l15 * 128 + (((kt * 4 + quad) ^ (l15 & 7)) * 16);
    int vAddr[2];
#pragma unroll
    for (int g = 0; g < 2; ++g)
        vAddr[g] = 8192 + l15 * 128 + (((g * 4 + quad) ^ (l15 & 7)) * 16);

    const f32x4 z4 = (f32x4)0.0f;
    const bfrag4 ones = {0x3F80, 0x3F80, 0x3F80, 0x3F80};  // bf16 1.0 x4

    f32x4 oacc[2][4], ol[2];
#pragma unroll
    for (int hf = 0; hf < 2; ++hf) {
        ol[hf] = z4;
#pragma unroll
        for (int dt = 0; dt < 4; ++dt) oacc[hf][dt] = z4;
    }

    // prologue: stage tile 0 into buffer 0
#pragma unroll
    for (int i = 0; i < 2; ++i) {
        gload_lds16(kBase + ksrc[i], smem + wave * 2048 + i * 1024);
        gload_lds16(vBase + vsrc[i], smem + 8192 + wave * 2048 + i * 1024);
    }

    auto astep = [&](int CUR, int NXT, int jn, int pref) {
        __syncthreads();   // tile-j loads landed; prior compute done (buffer free)
        if (pref) {
#pragma unroll
            for (int i = 0; i < 2; ++i) {
                gload_lds16(kBase + jn * 8192 + ksrc[i], smem + NXT + wave * 2048 + i * 1024);
                gload_lds16(vBase + jn * 128  + vsrc[i], smem + NXT + 8192 + wave * 2048 + i * 1024);
            }
        }

        // mask (pre-multiplied by log2e) == C-layout broadcast -> QK acc init
        f32x4 mvl[4];
#pragma unroll
        for (int ct = 0; ct < 4; ++ct)
            mvl[ct] = *(const f32x4*)(mSrc + ct * 64);
        mSrc += 256;

        // S^T = K * Q^T + mask : both halves share each kf read
        f32x4 s0[4], s1[4];
#pragma unroll
        for (int ct = 0; ct < 4; ++ct) {
            bfrag kf0 = *(const bfrag*)(smem + CUR + kAddr[0] + ct * 2048);
            bfrag kf1 = *(const bfrag*)(smem + CUR + kAddr[1] + ct * 2048);
            s0[ct] = __builtin_amdgcn_mfma_f32_16x16x32_bf16(kf0, qf[0][0], mvl[ct], 0, 0, 0);
            s0[ct] = __builtin_amdgcn_mfma_f32_16x16x32_bf16(kf1, qf[0][1], s0[ct],  0, 0, 0);
            s1[ct] = __builtin_amdgcn_mfma_f32_16x16x32_bf16(kf0, qf[1][0], mvl[ct], 0, 0, 0);
            s1[ct] = __builtin_amdgcn_mfma_f32_16x16x32_bf16(kf1, qf[1][1], s1[ct],  0, 0, 0);
        }

        // softmax numerators: 32 exp + 16 pack per iter (both halves)
        bfrag4 pf0[4], pf1[4];
#pragma unroll
        for (int ct = 0; ct < 4; ++ct) {
            union { uint32_t u[2]; bfrag4 v; } cvt;
            cvt.u[0] = pack_bf16(__builtin_amdgcn_exp2f(s0[ct][0]), __builtin_amdgcn_exp2f(s0[ct][1]));
            cvt.u[1] = pack_bf16(__builtin_amdgcn_exp2f(s0[ct][2]), __builtin_amdgcn_exp2f(s0[ct][3]));
            pf0[ct] = cvt.v;
            cvt.u[0] = pack_bf16(__builtin_amdgcn_exp2f(s1[ct][0]), __builtin_amdgcn_exp2f(s1[ct][1]));
            cvt.u[1] = pack_bf16(__builtin_amdgcn_exp2f(s1[ct][2]), __builtin_amdgcn_exp2f(s1[ct][3]));
            pf1[ct] = cvt.v;
        }

        // O += P*V : one b128 V read feeds 4 MFMAs (2 halves x MFMA pair)
#pragma unroll
        for (int dt = 0; dt < 4; ++dt) {
#pragma unroll
            for (int g = 0; g < 2; ++g) {
                bfrag v = *(const bfrag*)(smem + CUR + vAddr[g] + dt * 2048);
                bfrag4 vlo = __builtin_shufflevector(v, v, 0, 1, 2, 3);
                bfrag4 vhi = __builtin_shufflevector(v, v, 4, 5, 6, 7);
                oacc[0][dt] = __builtin_amdgcn_mfma_f32_16x16x16bf16_1k(pf0[2 * g],     vlo, oacc[0][dt], 0, 0, 0);
                oacc[0][dt] = __builtin_amdgcn_mfma_f32_16x16x16bf16_1k(pf0[2 * g + 1], vhi, oacc[0][dt], 0, 0, 0);
                oacc[1][dt] = __builtin_amdgcn_mfma_f32_16x16x16bf16_1k(pf1[2 * g],     vlo, oacc[1][dt], 0, 0, 0);
                oacc[1][dt] = __builtin_amdgcn_mfma_f32_16x16x16bf16_1k(pf1[2 * g + 1], vhi, oacc[1][dt], 0, 0, 0);
            }
        }
#pragma unroll
        for (int ct = 0; ct < 4; ++ct) {
            ol[0] = __builtin_amdgcn_mfma_f32_16x16x16bf16_1k(pf0[ct], ones, ol[0], 0, 0, 0);
            ol[1] = __builtin_amdgcn_mfma_f32_16x16x16bf16_1k(pf1[ct], ones, ol[1], 0, 0, 0);
        }
    };

    for (int jj = 0; jj < 16; ++jj) {
        astep(0,     16384, 2 * jj + 1, 1);
        astep(16384, 0,     2 * jj + 2, jj < 15);
    }

    // epilogue: out[b][qrow][h*64+d] fp32; O rows = quad*4+r, cols = l15 (+16*dt)
#pragma unroll
    for (int hf = 0; hf < 2; ++hf) {
#pragma unroll
        for (int r = 0; r < 4; ++r) {
            float linv = 1.0f / ol[hf][r];
            int qrow = qBase + hf * 16 + quad * 4 + r;
#pragma unroll
            for (int dt = 0; dt < 4; ++dt)
                out[((size_t)(b * SS + qrow)) * HH + h * 64 + dt * 16 + l15] =
                    oacc[hf][dt][r] * linv;
        }
    }
}

extern "C" void kernel_launch(void* const* d_in, const int* in_sizes, int n_in,
                              void* d_out, int out_size, void* d_ws, size_t ws_size,
                              hipStream_t stream) {
    const float* hs   = (const float*)d_in[0];
    const float* mask = (const float*)d_in[1];
    const float* Wq   = (const float*)d_in[2];
    const float* bq   = (const float*)d_in[3];
    const float* Wk   = (const float*)d_in[4];
    const float* bk   = (const float*)d_in[5];
    const float* Wv   = (const float*)d_in[6];
    const float* bv   = (const float*)d_in[7];
    float* out = (float*)d_out;

    char* ws = (char*)d_ws;
    short* Xb    = (short*)(ws);                      // [4096][1024] bf16, 8 MiB
    short* Wcat  = (short*)(ws + (8ull  << 20));      // [3072][1024] bf16, 6 MiB (Wq|Wk|Wv)
    short* Qb    = (short*)(ws + (14ull << 20));      // [bh][s][d] 8 MiB (pre-scaled)
    short* Kb    = (short*)(ws + (22ull << 20));      // [bh][s][d] 8 MiB
    short* Vb    = (short*)(ws + (30ull << 20));      // [bh][d][s-permuted] 8 MiB
    float* maskl = (float*)(ws + (38ull << 20));      // [B][S] fp32, 16 KiB

    cvt_all<<<7172, 256, 0, stream>>>(hs, Wq, Wk, Wv, mask, Xb, Wcat, maskl);

    qkv_gemm<<<dim3(24, 32), 256, 0, stream>>>(Xb, Wcat, bq, bk, bv, Qb, Kb, Vb);

    attn_kernel<<<512, 256, 0, stream>>>(Qb, Kb, Vb, maskl, out);
}

// Round 14
// 158.283 us; speedup vs baseline: 1.0716x; 1.0463x over previous
//
#include <hip/hip_runtime.h>
#include <stdint.h>

// Problem constants
#define BB 2
#define SS 2048
#define HH 1024
#define NH 16
#define HD 64

#define LOG2E 1.4426950408889634f
#define QSCALE (0.125f * LOG2E)   // folded into Q at GEMM epilogue

typedef short bfrag  __attribute__((ext_vector_type(8)));   // 8 x bf16 (4 VGPRs)
typedef short bfrag4 __attribute__((ext_vector_type(4)));   // 4 x bf16 (2 VGPRs)
typedef float f32x4  __attribute__((ext_vector_type(4)));

__device__ __forceinline__ short f2bf(float f) {
    union { float f; uint32_t u; } v; v.f = f;
    uint32_t r = (v.u + 0x7fffu + ((v.u >> 16) & 1u)) >> 16;
    return (short)r;
}

// pack two f32 -> one dword of bf16 (lo = a, hi = b)
__device__ __forceinline__ uint32_t pack_bf16(float a, float b) {
#if __has_builtin(__builtin_amdgcn_cvt_pk_bf16_f32)
    auto t = __builtin_amdgcn_cvt_pk_bf16_f32(a, b);   // RNE, single VALU op
    uint32_t u; __builtin_memcpy(&u, &t, 4);
    return u;
#else
    uint32_t ua = __float_as_uint(a) + 0x8000u;
    uint32_t ub = __float_as_uint(b) + 0x8000u;
    return __builtin_amdgcn_perm(ub, ua, 0x07060302u);
#endif
}

// fused fp32->bf16 conversion: hidden (1048576 f4) + Wq/Wk/Wv (262144 f4 each,
// into contiguous Wcat) + mask*LOG2E (1024 f4, fp32 out). grid 7172.
__global__ __launch_bounds__(256) void cvt_all(
    const float* __restrict__ X,  const float* __restrict__ Wq,
    const float* __restrict__ Wk, const float* __restrict__ Wv,
    const float* __restrict__ mask,
    short* __restrict__ Xb, short* __restrict__ Wcat,
    float* __restrict__ maskl)
{
    int i = blockIdx.x * 256 + threadIdx.x;
    if (i >= 1835008) {
        int off = i - 1835008;   // 0..1023
        float4 f = ((const float4*)mask)[off];
        f.x *= LOG2E; f.y *= LOG2E; f.z *= LOG2E; f.w *= LOG2E;
        ((float4*)maskl)[off] = f;
        return;
    }
    const float* src; short* dst; int off;
    if (i < 1048576)      { src = X;  dst = Xb;                 off = i; }
    else if (i < 1310720) { src = Wq; dst = Wcat;               off = i - 1048576; }
    else if (i < 1572864) { src = Wk; dst = Wcat + 1048576;     off = i - 1310720; }
    else                  { src = Wv; dst = Wcat + 2097152;     off = i - 1572864; }
    float4 f = ((const float4*)src)[off];
    short4 s;
    s.x = f2bf(f.x); s.y = f2bf(f.y); s.z = f2bf(f.z); s.w = f2bf(f.w);
    ((short4*)dst)[off] = s;
}

__device__ __forceinline__ void gload_lds16(const void* g, void* lds) {
    __builtin_amdgcn_global_load_lds(
        (__attribute__((address_space(1))) void*)(uintptr_t)g,
        (__attribute__((address_space(3))) void*)(uintptr_t)lds,
        16, 0, 0);
}

// Fused QKV GEMM (BK=64, 2-barrier K-loop, (256,3) — known-good config).
// C[m][n] = sum_k X[m][k] * Wcat[n][k] + bias, M=4096 N=3072 K=1024.
// n in [0,1024) -> Q (pre-scaled by QSCALE), [1024,2048) -> K,
// [2048,3072) -> V^T [bh][d][s] with k-PERMUTED s within each 64-block:
// pos(k) = (g*4+q)*8 + h*4 + j for k = 32g+16h+4q+j. This order is
// simultaneously the K=32 PV B-operand k-order (see attn).
__global__ __launch_bounds__(256, 3) void qkv_gemm(
    const short* __restrict__ X, const short* __restrict__ Wcat,
    const float* __restrict__ bq, const float* __restrict__ bk, const float* __restrict__ bv,
    short* __restrict__ Qo, short* __restrict__ Ko, short* __restrict__ Vo)
{
    // main loop: As = smem[0..8191], Bs = smem[8192..16383] (shorts)
    // epilogue: reused as T[128][136] (17408 shorts)
    __shared__ __align__(16) short smem[17408];

    const int tid  = threadIdx.x;
    const int wave = tid >> 6, lane = tid & 63;
    const int quad = lane >> 4, l15 = lane & 15;
    const int mTile = blockIdx.y * 128;
    const int nTile = blockIdx.x * 128;
    const int z = nTile >> 10;                 // 0=Q,1=K,2=V (block-uniform)
    const int nLocT = nTile & 1023;
    const float* bias = (z == 0) ? bq : (z == 1) ? bk : bv;

    f32x4 acc[4][4];
#pragma unroll
    for (int i = 0; i < 4; ++i)
#pragma unroll
        for (int j = 0; j < 4; ++j) acc[i][j] = (f32x4)0.0f;

    const int srow  = lane >> 3;   // 0..7
    const int c_lin = lane & 7;
    const int mBase = (wave >> 1) * 64;
    const int nBase = (wave & 1) * 64;

    for (int k0 = 0; k0 < 1024; k0 += 64) {
        __syncthreads();
#pragma unroll
        for (int i = 0; i < 4; ++i) {
            int row = i * 32 + wave * 8 + srow;
            int cg  = c_lin ^ (row & 7);
            gload_lds16(X + (size_t)(mTile + row) * 1024 + k0 + cg * 8,
                        (char*)smem + i * 4096 + wave * 1024);
            gload_lds16(Wcat + (size_t)(nTile + row) * 1024 + k0 + cg * 8,
                        (char*)smem + 16384 + i * 4096 + wave * 1024);
        }
        __syncthreads();

#pragma unroll
        for (int kt = 0; kt < 2; ++kt) {
            bfrag af[4], bf[4];
#pragma unroll
            for (int t = 0; t < 4; ++t) {
                int arow = mBase + t * 16 + l15;
                int aslot = (kt * 4 + quad) ^ (arow & 7);
                af[t] = *(const bfrag*)((const char*)smem + arow * 128 + aslot * 16);
                int brow = nBase + t * 16 + l15;
                int bslot = (kt * 4 + quad) ^ (brow & 7);
                bf[t] = *(const bfrag*)((const char*)smem + 16384 + brow * 128 + bslot * 16);
            }
#pragma unroll
            for (int mt = 0; mt < 4; ++mt)
#pragma unroll
                for (int ct = 0; ct < 4; ++ct)
                    acc[mt][ct] = __builtin_amdgcn_mfma_f32_16x16x32_bf16(
                        af[mt], bf[ct], acc[mt][ct], 0, 0, 0);
        }
    }

    __syncthreads();   // main-loop LDS reads complete before T overwrite
    const int b = mTile >> 11, sBase = mTile & 2047;

    if (z == 2) {
        // T[n-local][s-local], pitch 136 -> k-permuted coalesced V^T stores
#pragma unroll
        for (int mt = 0; mt < 4; ++mt)
#pragma unroll
            for (int ct = 0; ct < 4; ++ct)
#pragma unroll
                for (int r = 0; r < 4; ++r) {
                    int nl = nBase + ct * 16 + l15;
                    int sl = mBase + mt * 16 + quad * 4 + r;
                    smem[nl * 136 + sl] = f2bf(acc[mt][ct][r] + bias[nLocT + nl]);
                }
        __syncthreads();
#pragma unroll
        for (int p = 0; p < 8; ++p) {
            int nl = p * 16 + (tid >> 4);     // d-row 0..127
            int cg = tid & 15;                // 16B chunk within 128-s tile
            int blk = cg >> 3;                // which 64-s block
            int c2  = cg & 7;                 // chunk within block: g = c2>>2, q = c2&3
            int base = blk * 64 + (c2 >> 2) * 32 + (c2 & 3) * 4;   // h=0 source
            int2 lo = *(const int2*)(smem + nl * 136 + base);       // k = ..+0..3
            int2 hi = *(const int2*)(smem + nl * 136 + base + 16);  // k = ..+16..19
            int4 v; v.x = lo.x; v.y = lo.y; v.z = hi.x; v.w = hi.y;
            int ng = nLocT + nl, hh = ng >> 6, d = ng & 63;
            *(int4*)(Vo + ((size_t)(b * 16 + hh) * 64 + d) * 2048 + sBase + cg * 8) = v;
        }
    } else {
        short* Out = (z == 0) ? Qo : Ko;
        float scale = (z == 0) ? QSCALE : 1.0f;
        // T[s-local][n-local], pitch 136 -> coalesced [bh][s][d] stores
#pragma unroll
        for (int mt = 0; mt < 4; ++mt)
#pragma unroll
            for (int ct = 0; ct < 4; ++ct)
#pragma unroll
                for (int r = 0; r < 4; ++r) {
                    int ml = mBase + mt * 16 + quad * 4 + r;
                    int nl = nBase + ct * 16 + l15;
                    smem[ml * 136 + nl] = f2bf((acc[mt][ct][r] + bias[nLocT + nl]) * scale);
                }
        __syncthreads();
#pragma unroll
        for (int p = 0; p < 8; ++p) {
            int ml = p * 16 + (tid >> 4);
            int c  = tid & 15;
            bfrag v8 = *(const bfrag*)(smem + ml * 136 + c * 8);
            int s  = sBase + ml;
            int nl = nLocT + c * 8, hh = nl >> 6, d = nl & 63;
            *(bfrag*)(Out + (((size_t)(b * 16 + hh) << 11) + s) * 64 + d) = v8;
        }
    }
}

// Flash attention (no-max softmax, log2 domain; Q pre-scaled by 0.125*log2e).
// 32 Q-rows per wave (two 16-row halves sharing every K/V LDS read).
// PV and l-sum now use mfma_f32_16x16x32_bf16 (full-rate on gfx950) instead of
// the legacy half-rate 16x16x16_1k: A = concat(pf[2g], pf[2g+1]) whose k-order
// exactly matches the k-permuted V chunk (key 32g+16h+4q+j at pos 4h+j) -> one
// b128 V read is directly the K=32 B-operand. PV MFMA instr 32->16, l 8->4.
// 4-wave blocks of 128 Q rows; grid 512. XCD-affinity: 4 bh per XCD (K+V 2MB
// L2-resident). Bc=64; LDS double-buffer with DMA staging, ONE barrier/iter.
// Mask folded into QK MFMA C-operand; P packed via v_cvt_pk_bf16_f32.
__global__ __launch_bounds__(256, 2) void attn_kernel(
    const short* __restrict__ Qb, const short* __restrict__ Kb, const short* __restrict__ Vb,
    const float* __restrict__ maskl, float* __restrict__ out)
{
    __shared__ __align__(16) char smem[32768];
    // stage = 16384 B: K tile [64][64] bf16 @+0 (128B rows, XOR-swizzled 16B chunks),
    //                  V^T tile [64 d][64 k-permuted] bf16 @+8192 (same layout)

    const int tid  = threadIdx.x;
    const int wave = tid >> 6, lane = tid & 63;
    const int quad = lane >> 4, l15 = lane & 15;

    // XCD-affinity remap of the 512-block launch
    const int id = blockIdx.x;
    const int slot = id >> 3;                            // 0..63
    const int bh = ((id & 7) << 2) | (slot & 3);         // 0..31, fixed per XCD
    const int qt = slot >> 2;                            // 0..15
    const int b  = bh >> 4, h = bh & 15;
    const int qBase = qt * 128 + wave * 32;

    // staging source byte offsets (wave handles chunks wave*128 + i*64 + lane)
    int ksrc[2], vsrc[2];
#pragma unroll
    for (int i = 0; i < 2; ++i) {
        int ci = wave * 128 + i * 64 + lane;
        int r = ci >> 3, c = ci & 7;
        int cs = (c ^ (r & 7)) * 16;
        ksrc[i] = r * 128  + cs;    // K source: row stride 64 shorts = 128B
        vsrc[i] = r * 4096 + cs;    // V^T source: row stride 2048 shorts = 4096B
    }
    const char* kBase = (const char*)(Kb + (size_t)bh * SS * HD);
    const char* vBase = (const char*)(Vb + (size_t)bh * HD * SS);
    const char* mSrc  = (const char*)(maskl + b * SS) + quad * 16;

    // Q fragments (MFMA B-operand): Q[qrow=hf*16+l15][k=quad*8+j], pre-scaled
    const short* Qp = Qb + ((size_t)bh * SS + qBase) * HD;
    bfrag qf[2][2];
#pragma unroll
    for (int hf = 0; hf < 2; ++hf)
#pragma unroll
        for (int kt = 0; kt < 2; ++kt)
            qf[hf][kt] = *(const bfrag*)(Qp + (size_t)(hf * 16 + l15) * HD + kt * 32 + quad * 8);

    // j-invariant LDS read offsets (within a stage)
    int kAddr[2];
#pragma unroll
    for (int kt = 0; kt < 2; ++kt)
        kAddr[kt] = l15 * 128 + (((kt * 4 + quad) ^ (l15 & 7)) * 16);
    int vAddr[2];
#pragma unroll
    for (int g = 0; g < 2; ++g)
        vAddr[g] = 8192 + l15 * 128 + (((g * 4 + quad) ^ (l15 & 7)) * 16);

    const f32x4 z4 = (f32x4)0.0f;
    const bfrag ones8 = {0x3F80, 0x3F80, 0x3F80, 0x3F80,
                         0x3F80, 0x3F80, 0x3F80, 0x3F80};  // bf16 1.0 x8

    f32x4 oacc[2][4], ol[2];
#pragma unroll
    for (int hf = 0; hf < 2; ++hf) {
        ol[hf] = z4;
#pragma unroll
        for (int dt = 0; dt < 4; ++dt) oacc[hf][dt] = z4;
    }

    // prologue: stage tile 0 into buffer 0
#pragma unroll
    for (int i = 0; i < 2; ++i) {
        gload_lds16(kBase + ksrc[i], smem + wave * 2048 + i * 1024);
        gload_lds16(vBase + vsrc[i], smem + 8192 + wave * 2048 + i * 1024);
    }

    auto astep = [&](int CUR, int NXT, int jn, int pref) {
        __syncthreads();   // tile-j loads landed; prior compute done (buffer free)
        if (pref) {
#pragma unroll
            for (int i = 0; i < 2; ++i) {
                gload_lds16(kBase + jn * 8192 + ksrc[i], smem + NXT + wave * 2048 + i * 1024);
                gload_lds16(vBase + jn * 128  + vsrc[i], smem + NXT + 8192 + wave * 2048 + i * 1024);
            }
        }

        // mask (pre-multiplied by log2e) == C-layout broadcast -> QK acc init
        f32x4 mvl[4];
#pragma unroll
        for (int ct = 0; ct < 4; ++ct)
            mvl[ct] = *(const f32x4*)(mSrc + ct * 64);
        mSrc += 256;

        // S^T = K * Q^T + mask : both halves share each kf read
        f32x4 s0[4], s1[4];
#pragma unroll
        for (int ct = 0; ct < 4; ++ct) {
            bfrag kf0 = *(const bfrag*)(smem + CUR + kAddr[0] + ct * 2048);
            bfrag kf1 = *(const bfrag*)(smem + CUR + kAddr[1] + ct * 2048);
            s0[ct] = __builtin_amdgcn_mfma_f32_16x16x32_bf16(kf0, qf[0][0], mvl[ct], 0, 0, 0);
            s0[ct] = __builtin_amdgcn_mfma_f32_16x16x32_bf16(kf1, qf[0][1], s0[ct],  0, 0, 0);
            s1[ct] = __builtin_amdgcn_mfma_f32_16x16x32_bf16(kf0, qf[1][0], mvl[ct], 0, 0, 0);
            s1[ct] = __builtin_amdgcn_mfma_f32_16x16x32_bf16(kf1, qf[1][1], s1[ct],  0, 0, 0);
        }

        // softmax numerators: 32 exp + 16 pack per iter, packed directly into
        // K=32 A-frags: p[g] = concat(pf[2g], pf[2g+1]) (k-order matches V chunk)
        bfrag p0[2], p1[2];
#pragma unroll
        for (int g = 0; g < 2; ++g) {
            union { uint32_t u[4]; bfrag v; } cvt;
            cvt.u[0] = pack_bf16(__builtin_amdgcn_exp2f(s0[2*g][0]),   __builtin_amdgcn_exp2f(s0[2*g][1]));
            cvt.u[1] = pack_bf16(__builtin_amdgcn_exp2f(s0[2*g][2]),   __builtin_amdgcn_exp2f(s0[2*g][3]));
            cvt.u[2] = pack_bf16(__builtin_amdgcn_exp2f(s0[2*g+1][0]), __builtin_amdgcn_exp2f(s0[2*g+1][1]));
            cvt.u[3] = pack_bf16(__builtin_amdgcn_exp2f(s0[2*g+1][2]), __builtin_amdgcn_exp2f(s0[2*g+1][3]));
            p0[g] = cvt.v;
            cvt.u[0] = pack_bf16(__builtin_amdgcn_exp2f(s1[2*g][0]),   __builtin_amdgcn_exp2f(s1[2*g][1]));
            cvt.u[1] = pack_bf16(__builtin_amdgcn_exp2f(s1[2*g][2]),   __builtin_amdgcn_exp2f(s1[2*g][3]));
            cvt.u[2] = pack_bf16(__builtin_amdgcn_exp2f(s1[2*g+1][0]), __builtin_amdgcn_exp2f(s1[2*g+1][1]));
            cvt.u[3] = pack_bf16(__builtin_amdgcn_exp2f(s1[2*g+1][2]), __builtin_amdgcn_exp2f(s1[2*g+1][3]));
            p1[g] = cvt.v;
        }

        // O += P*V : one b128 V read == K=32 B-operand, feeds both halves
#pragma unroll
        for (int dt = 0; dt < 4; ++dt) {
#pragma unroll
            for (int g = 0; g < 2; ++g) {
                bfrag v = *(const bfrag*)(smem + CUR + vAddr[g] + dt * 2048);
                oacc[0][dt] = __builtin_amdgcn_mfma_f32_16x16x32_bf16(p0[g], v, oacc[0][dt], 0, 0, 0);
                oacc[1][dt] = __builtin_amdgcn_mfma_f32_16x16x32_bf16(p1[g], v, oacc[1][dt], 0, 0, 0);
            }
        }
#pragma unroll
        for (int g = 0; g < 2; ++g) {
            ol[0] = __builtin_amdgcn_mfma_f32_16x16x32_bf16(p0[g], ones8, ol[0], 0, 0, 0);
            ol[1] = __builtin_amdgcn_mfma_f32_16x16x32_bf16(p1[g], ones8, ol[1], 0, 0, 0);
        }
    };

    for (int jj = 0; jj < 16; ++jj) {
        astep(0,     16384, 2 * jj + 1, 1);
        astep(16384, 0,     2 * jj + 2, jj < 15);
    }

    // epilogue: out[b][qrow][h*64+d] fp32; O rows = quad*4+r, cols = l15 (+16*dt)
#pragma unroll
    for (int hf = 0; hf < 2; ++hf) {
#pragma unroll
        for (int r = 0; r < 4; ++r) {
            float linv = 1.0f / ol[hf][r];
            int qrow = qBase + hf * 16 + quad * 4 + r;
#pragma unroll
            for (int dt = 0; dt < 4; ++dt)
                out[((size_t)(b * SS + qrow)) * HH + h * 64 + dt * 16 + l15] =
                    oacc[hf][dt][r] * linv;
        }
    }
}

extern "C" void kernel_launch(void* const* d_in, const int* in_sizes, int n_in,
                              void* d_out, int out_size, void* d_ws, size_t ws_size,
                              hipStream_t stream) {
    const float* hs   = (const float*)d_in[0];
    const float* mask = (const float*)d_in[1];
    const float* Wq   = (const float*)d_in[2];
    const float* bq   = (const float*)d_in[3];
    const float* Wk   = (const float*)d_in[4];
    const float* bk   = (const float*)d_in[5];
    const float* Wv   = (const float*)d_in[6];
    const float* bv   = (const float*)d_in[7];
    float* out = (float*)d_out;

    char* ws = (char*)d_ws;
    short* Xb    = (short*)(ws);                      // [4096][1024] bf16, 8 MiB
    short* Wcat  = (short*)(ws + (8ull  << 20));      // [3072][1024] bf16, 6 MiB (Wq|Wk|Wv)
    short* Qb    = (short*)(ws + (14ull << 20));      // [bh][s][d] 8 MiB (pre-scaled)
    short* Kb    = (short*)(ws + (22ull << 20));      // [bh][s][d] 8 MiB
    short* Vb    = (short*)(ws + (30ull << 20));      // [bh][d][s-permuted] 8 MiB
    float* maskl = (float*)(ws + (38ull << 20));      // [B][S] fp32, 16 KiB

    cvt_all<<<7172, 256, 0, stream>>>(hs, Wq, Wk, Wv, mask, Xb, Wcat, maskl);

    qkv_gemm<<<dim3(24, 32), 256, 0, stream>>>(Xb, Wcat, bq, bk, bv, Qb, Kb, Vb);

    attn_kernel<<<512, 256, 0, stream>>>(Qb, Kb, Vb, maskl, out);
}